// Round 10
// baseline (529.623 us; speedup 1.0000x reference)
//
#include <hip/hip_runtime.h>
#include <hip/hip_fp16.h>

#define N_NODES 40000
#define N_EDGES 400000
#define N_GRAPHS 64
#define D1 256      // heads*hid for conv1
#define HIDC 64
#define NHEADS 4
#define EDIM 18
#define EPAD 20     // padded ea_s row stride; slots 18,19 hold x[src]
#define OUTF 3
#define APAD 264    // LDS row stride in halfs (256 + 8 pad -> 2-way bank alias only)

typedef _Float16 f16x8 __attribute__((ext_vector_type(8)));
typedef float f32x4 __attribute__((ext_vector_type(4)));

// ---------------- prep: pack conv2 weights + conv1 cbuf (one launch) --------
__global__ void prep_w(const float* __restrict__ Wq, const float* __restrict__ bq,
                       const float* __restrict__ Wk, const float* __restrict__ bk,
                       const float* __restrict__ Wv, const float* __restrict__ bv,
                       const float* __restrict__ Ws, const float* __restrict__ bs,
                       const float* __restrict__ We2,
                       const float* __restrict__ Wq1, const float* __restrict__ bq1,
                       const float* __restrict__ Wk1, const float* __restrict__ bk1,
                       const float* __restrict__ We1,
                       __half* __restrict__ Bt, float* __restrict__ bias,
                       float* __restrict__ cbuf) {
    int c = blockIdx.x, k = threadIdx.x;
    if (c < 256) {
        int m = c >> 6, d = c & 63;
        const float* W = (m == 0) ? Wq : (m == 1) ? Wk : (m == 2) ? Wv : Ws;
        Bt[c * 256 + k] = __float2half(W[k * 64 + d]);
        if (k == 0) {
            const float* b = (m == 0) ? bq : (m == 1) ? bk : (m == 2) ? bv : bs;
            bias[c] = b[d];
        }
    } else if (c < 288) {
        int j = c - 256;
        float s = 0.f;
        if (j < EDIM)
            for (int cc = 0; cc < 64; ++cc) s += Wq[k * 64 + cc] * We2[j * 64 + cc];
        Bt[c * 256 + k] = __float2half(s);
        if (k == 0) {
            float b = 0.f;
            if (j < EDIM)
                for (int cc = 0; cc < 64; ++cc) b += bq[cc] * We2[j * 64 + cc];
            bias[c] = b;
        }
    } else {
        int t = k;
        if (t < 36) {
            int h = t / 9, r = t % 9, a = r / 3, b = r % 3;
            const float* A = (a == 0) ? Wq1 : (a == 1) ? Wq1 + D1 : bq1;
            const float* B = (b == 0) ? Wk1 : (b == 1) ? Wk1 + D1 : bk1;
            float s = 0.f;
            for (int cc = 0; cc < 64; ++cc) s += A[h * 64 + cc] * B[h * 64 + cc];
            cbuf[h * 63 + a * 3 + b] = s;
        } else if (t < 252) {
            int i = t - 36;
            int h = i / 54, rr = (i % 54) / 18, j = i % 18;
            const float* A = (rr == 0) ? Wq1 : (rr == 1) ? Wq1 + D1 : bq1;
            float s = 0.f;
            for (int cc = 0; cc < 64; ++cc) s += A[h * 64 + cc] * We1[j * D1 + h * 64 + cc];
            cbuf[h * 63 + 9 + rr * 18 + j] = s;
        }
    }
}

// ---------------- init + conv1 coef table (merged) ----------------
__global__ void initA(const float* __restrict__ x, const float* __restrict__ cbuf,
                      float* __restrict__ coef, float* __restrict__ acc1,
                      float* __restrict__ acc2, float* __restrict__ out2,
                      int* __restrict__ deg, float* __restrict__ pooled,
                      int* __restrict__ gs, int* __restrict__ ge) {
    int t = blockIdx.x * 256 + threadIdx.x;      // N*84 threads exact
    acc1[t] = 0.f;
    {
        int n = t / 84, r = t % 84, h = r / 21, c = r % 21;
        const float* cb = cbuf + h * 63;
        float x0 = x[2 * n], x1 = x[2 * n + 1], o;
        if (c < 3) o = x0 * cb[c] + x1 * cb[3 + c] + cb[6 + c];
        else { int j = c - 3; o = x0 * cb[9 + j] + x1 * cb[27 + j] + cb[45 + j]; }
        coef[t] = o;
    }
    if (t < N_NODES * 64) out2[t] = 0.f;
    if (t < N_NODES * 20) acc2[t] = 0.f;
    if (t < N_NODES) deg[t] = 0;
    if (t < N_GRAPHS * HIDC) pooled[t] = 0.f;
    if (t < N_GRAPHS) { gs[t] = 0; ge[t] = 0; }
}

// ---------------- CSR hist + graph bounds (merged) ----------------
__global__ void hist_kernel(const int* __restrict__ ei, int* __restrict__ deg,
                            const int* __restrict__ batch, int* __restrict__ gs,
                            int* __restrict__ ge) {
    int e = blockIdx.x * 256 + threadIdx.x;
    if (e < N_EDGES) atomicAdd(&deg[ei[N_EDGES + e]], 1);
    int n = e;
    if (n < N_NODES) {
        int b = batch[n];
        if (n == 0) gs[b] = 0;
        else { int pb = batch[n - 1]; if (pb != b) { ge[pb] = n; gs[b] = n; } }
        if (n == N_NODES - 1) ge[b] = N_NODES;
    }
}

// ---------------- single-block exclusive scan -> cursor ----------------
__global__ void scan_kernel(const int* __restrict__ deg, int* __restrict__ cursor) {
    __shared__ int sums[1024];
    int t = threadIdx.x;
    const int PER = 40;
    int base = t * PER;
    int s = 0;
    for (int i = 0; i < PER; ++i) { int idx = base + i; if (idx < N_NODES) s += deg[idx]; }
    sums[t] = s;
    __syncthreads();
    for (int off = 1; off < 1024; off <<= 1) {
        int v = sums[t];
        int w = (t >= off) ? sums[t - off] : 0;
        __syncthreads();
        sums[t] = v + w;
        __syncthreads();
    }
    int run = (t == 0) ? 0 : sums[t - 1];
    for (int i = 0; i < PER; ++i) {
        int idx = base + i;
        if (idx < N_NODES) { cursor[idx] = run; run += deg[idx]; }
    }
}

// ---------------- 2-phase CSR scatter: perm (4B) then coalesced gather ------
__global__ void perm_kernel(const int* __restrict__ ei, int* __restrict__ cursor,
                            int* __restrict__ inv) {
    int e = blockIdx.x * 256 + threadIdx.x;
    if (e >= N_EDGES) return;
    int p = atomicAdd(&cursor[ei[N_EDGES + e]], 1);
    inv[p] = e;
}

// ---------------- fused gather + conv1 logits (4 heads) ----------------
__global__ void gatherE(const int* __restrict__ inv, const int* __restrict__ ei,
                        const float* __restrict__ ea, const float* __restrict__ x,
                        const float* __restrict__ coef,
                        int* __restrict__ src_s, int* __restrict__ dst_s,
                        float* __restrict__ ea_s, float* __restrict__ alpha1) {
    int p = blockIdx.x * 256 + threadIdx.x;
    if (p >= N_EDGES) return;
    int e = inv[p];
    int src = ei[e], dst = ei[N_EDGES + e];
    src_s[p] = src;
    dst_s[p] = dst;
    const float* srow = ea + (size_t)e * EDIM;
    float s[EDIM];
    #pragma unroll
    for (int j = 0; j < EDIM; ++j) s[j] = srow[j];
    float x0 = x[src * 2], x1 = x[src * 2 + 1];
    float4* drow = (float4*)(ea_s + (size_t)p * EPAD);
    drow[0] = make_float4(s[0],  s[1],  s[2],  s[3]);
    drow[1] = make_float4(s[4],  s[5],  s[6],  s[7]);
    drow[2] = make_float4(s[8],  s[9],  s[10], s[11]);
    drow[3] = make_float4(s[12], s[13], s[14], s[15]);
    drow[4] = make_float4(s[16], s[17], x0, x1);
    const float* cb = coef + (size_t)dst * 84;
    #pragma unroll
    for (int h = 0; h < NHEADS; ++h) {
        const float* c = cb + h * 21;
        float a = x0 * c[0] + x1 * c[1] + c[2];
        #pragma unroll
        for (int j = 0; j < EDIM; ++j) a += s[j] * c[3 + j];
        alpha1[(size_t)h * N_EDGES + p] = __expf(a * 0.125f);
    }
}

// ---------------- conv1: 16-edge strip, preloaded segmented reduction -------
__global__ void strip1(const int* __restrict__ dst_s, const float* __restrict__ alpha1,
                       const float* __restrict__ ea_s, float* __restrict__ acc1) {
    int t = threadIdx.x;
    int strip = blockIdx.x * 2 + (t >> 7);       // 2 strips per 256-block
    int gl = t & 127;
    bool active = gl < 84;
    int cgl = active ? gl : 83;
    int h = cgl / 21, comp = cgl % 21;
    int voff = (comp == 0) ? 18 : (comp == 1) ? 19 : (comp - 3);
    bool isone = (comp == 2);
    int p0 = strip * 16;
    int dsts[16]; float w[16]; float v[16];
    #pragma unroll
    for (int j = 0; j < 16; ++j) dsts[j] = dst_s[p0 + j];
    #pragma unroll
    for (int j = 0; j < 16; ++j) w[j] = alpha1[(size_t)h * N_EDGES + p0 + j];
    #pragma unroll
    for (int j = 0; j < 16; ++j) v[j] = isone ? 1.f : ea_s[(size_t)(p0 + j) * EPAD + voff];
    float acc = 0.f;
    int prev = dsts[0];
    #pragma unroll
    for (int j = 0; j < 16; ++j) {
        if (dsts[j] != prev) {
            if (active) atomicAdd(&acc1[(size_t)prev * 84 + gl], acc);
            acc = 0.f; prev = dsts[j];
        }
        acc += w[j] * v[j];
    }
    if (active) atomicAdd(&acc1[(size_t)prev * 84 + gl], acc);
}

// ---------------- conv1 finalize: 4 nodes/block, weights in regs ------------
__global__ void finalize1x(const float* __restrict__ x, const float* __restrict__ acc1,
                           const float* __restrict__ Wv, const float* __restrict__ bv,
                           const float* __restrict__ We, const float* __restrict__ Wskip,
                           const float* __restrict__ bskip, const float* __restrict__ Wbeta,
                           __half* __restrict__ h1f) {
    __shared__ float red[4][4];
    int nb = blockIdx.x * 4;
    int t = threadIdx.x;                          // column d
    int h = t >> 6;
    float wv0 = Wv[t], wv1 = Wv[D1 + t], bvv = bv[t];
    float we[EDIM];
    #pragma unroll
    for (int j = 0; j < EDIM; ++j) we[j] = We[j * D1 + t];
    float ws0 = Wskip[t], ws1 = Wskip[D1 + t], bsv = bskip[t];
    float wb0 = Wbeta[t], wb1 = Wbeta[D1 + t], wb2 = Wbeta[2 * D1 + t];
    float o[4], xr[4], part[4];
    #pragma unroll
    for (int i = 0; i < 4; ++i) {
        int node = nb + i;
        const float* a = acc1 + (size_t)node * 84 + h * 21;
        float l = a[2];
        float oo = a[0] * wv0 + a[1] * wv1 + l * bvv;
        #pragma unroll
        for (int j = 0; j < EDIM; ++j) oo += a[3 + j] * we[j];
        oo /= (l + 1e-16f);
        float x0 = x[node * 2], x1 = x[node * 2 + 1];
        xr[i] = x0 * ws0 + x1 * ws1 + bsv;
        o[i] = oo;
        part[i] = oo * wb0 + xr[i] * wb1 + (oo - xr[i]) * wb2;
    }
    #pragma unroll
    for (int off = 32; off; off >>= 1) {
        #pragma unroll
        for (int i = 0; i < 4; ++i) part[i] += __shfl_xor(part[i], off);
    }
    if ((t & 63) == 0) {
        #pragma unroll
        for (int i = 0; i < 4; ++i) red[h][i] = part[i];
    }
    __syncthreads();
    #pragma unroll
    for (int i = 0; i < 4; ++i) {
        float tot = red[0][i] + red[1][i] + red[2][i] + red[3][i];
        float beta = 1.f / (1.f + __expf(-tot));
        h1f[(size_t)(nb + i) * D1 + t] =
            __float2half(fmaxf(beta * xr[i] + (1.f - beta) * o[i], 0.f));
    }
}

// ---------------- conv2 linears via MFMA, LDS-staged A ----------------------
// Block = 64 rows: stage A (64x256 f16) coalesced into LDS (row pad +8 halfs),
// 4 waves each own ~5 col-tiles with B-frags in registers; A-frags via ds_read_b128.
__device__ __forceinline__ void nl2_store(int c, int gr, float v,
        float* __restrict__ q2, float* __restrict__ k2, __half* __restrict__ v2h,
        float* __restrict__ xr2, float* __restrict__ qe) {
    if (c < 256) {
        int m = c >> 6, d = c & 63;
        if (m == 0)      q2[(size_t)gr * 64 + d] = v;
        else if (m == 1) k2[(size_t)gr * 64 + d] = v;
        else if (m == 2) v2h[(size_t)gr * 64 + d] = __float2half(v);
        else             xr2[(size_t)gr * 64 + d] = v;
    } else {
        qe[(size_t)gr * 32 + (c - 256)] = v;
    }
}

__global__ __launch_bounds__(256) void nl2_mfma(
        const __half* __restrict__ h1f, const __half* __restrict__ Bt,
        const float* __restrict__ bias,
        float* __restrict__ q2, float* __restrict__ k2,
        __half* __restrict__ v2h, float* __restrict__ xr2,
        float* __restrict__ qe) {
    __shared__ _Float16 As[64 * APAD];
    int t = threadIdx.x;
    int row0 = blockIdx.x * 64;
    const float4* gsrc = (const float4*)(h1f + (size_t)row0 * 256);
    #pragma unroll
    for (int i = 0; i < 8; ++i) {
        int li = i * 256 + t;                 // chunk of 8 halfs
        int r = li >> 5, c8 = li & 31;
        *(float4*)(As + r * APAD + c8 * 8) = gsrc[li];
    }
    __syncthreads();
    int wave = t >> 6, lane = t & 63, quad = lane >> 4, mm = lane & 15;
    const _Float16* Bp = (const _Float16*)Bt;
    for (int ct = wave; ct < 18; ct += 4) {
        int c0 = ct * 16 + mm;
        const _Float16* b0 = Bp + (size_t)c0 * 256 + quad * 8;
        f16x8 b[8];
        #pragma unroll
        for (int s = 0; s < 8; ++s) b[s] = *(const f16x8*)(b0 + s * 32);
        float bz = bias[c0];
        #pragma unroll
        for (int rt = 0; rt < 4; ++rt) {
            const _Float16* arow = As + (rt * 16 + mm) * APAD + quad * 8;
            f16x8 a[8];
            #pragma unroll
            for (int s = 0; s < 8; ++s) a[s] = *(const f16x8*)(arow + s * 32);
            f32x4 accA = {bz, bz, bz, bz};
            f32x4 accB = {0.f, 0.f, 0.f, 0.f};
            #pragma unroll
            for (int s = 0; s < 4; ++s) {
                accA = __builtin_amdgcn_mfma_f32_16x16x32_f16(a[s],     b[s],     accA, 0, 0, 0);
                accB = __builtin_amdgcn_mfma_f32_16x16x32_f16(a[s + 4], b[s + 4], accB, 0, 0, 0);
            }
            #pragma unroll
            for (int r = 0; r < 4; ++r) {
                int gr = row0 + rt * 16 + quad * 4 + r;
                nl2_store(c0, gr, accA[r] + accB[r], q2, k2, v2h, xr2, qe);
            }
        }
    }
}

// ---------------- conv2: wave-per-edge logits, 2-edge unroll ----------------
#define LG2_BLOCKS 2048
#define LG2_WAVES (LG2_BLOCKS * 4)
__global__ void logits2(const int* __restrict__ src_s, const int* __restrict__ dst_s,
                        const float* __restrict__ ea_s, const float* __restrict__ q2,
                        const float* __restrict__ k2, const float* __restrict__ qe,
                        float* __restrict__ alpha2) {
    int t = threadIdx.x, wid = t >> 6, lane = t & 63;
    int w = blockIdx.x * 4 + wid;
    for (int base = w; base < N_EDGES; base += 2 * LG2_WAVES) {
        int p1 = base, p2 = base + LG2_WAVES;
        bool has2 = p2 < N_EDGES;
        int p2c = has2 ? p2 : p1;
        int s1 = src_s[p1], d1 = dst_s[p1];
        int s2 = src_s[p2c], d2 = dst_s[p2c];
        float dd1 = q2[(size_t)d1 * 64 + lane] * k2[(size_t)s1 * 64 + lane];
        float dd2 = q2[(size_t)d2 * 64 + lane] * k2[(size_t)s2 * 64 + lane];
        if (lane < 20) {
            dd1 += qe[(size_t)d1 * 32 + lane] * ea_s[(size_t)p1 * EPAD + lane];
            dd2 += qe[(size_t)d2 * 32 + lane] * ea_s[(size_t)p2c * EPAD + lane];
        }
        #pragma unroll
        for (int off = 32; off; off >>= 1) {
            dd1 += __shfl_xor(dd1, off);
            dd2 += __shfl_xor(dd2, off);
        }
        if (lane == 0) {
            alpha2[p1] = __expf(dd1 * 0.125f);
            if (has2) alpha2[p2] = __expf(dd2 * 0.125f);
        }
    }
}

// ---------------- conv2: 16-edge strip, preloaded: out2+=w*v, acc2+=w*[ea,1]-
__global__ void spmm2s(const int* __restrict__ dst_s, const int* __restrict__ src_s,
                       const float* __restrict__ alpha2, const __half* __restrict__ v2h,
                       const float* __restrict__ ea_s,
                       float* __restrict__ out2, float* __restrict__ acc2) {
    int t = threadIdx.x;
    int strip = blockIdx.x * 4 + (t >> 6);
    int lane = t & 63;
    int p0 = strip * 16;
    int dsts[16]; int srcs[16]; float w[16];
    #pragma unroll
    for (int j = 0; j < 16; ++j) dsts[j] = dst_s[p0 + j];
    #pragma unroll
    for (int j = 0; j < 16; ++j) srcs[j] = src_s[p0 + j];
    #pragma unroll
    for (int j = 0; j < 16; ++j) w[j] = alpha2[p0 + j];
    float vv[16]; float ev[16];
    #pragma unroll
    for (int j = 0; j < 16; ++j) vv[j] = __half2float(v2h[(size_t)srcs[j] * 64 + lane]);
    #pragma unroll
    for (int j = 0; j < 16; ++j)
        ev[j] = (lane < EDIM) ? ea_s[(size_t)(p0 + j) * EPAD + lane] : 1.f;
    float acc = 0.f, accS = 0.f;
    int prev = dsts[0];
    #pragma unroll
    for (int j = 0; j < 16; ++j) {
        if (dsts[j] != prev) {
            atomicAdd(&out2[(size_t)prev * 64 + lane], acc);
            if (lane < 19) atomicAdd(&acc2[(size_t)prev * 20 + lane], accS);
            acc = 0.f; accS = 0.f; prev = dsts[j];
        }
        acc += w[j] * vv[j];
        accS += w[j] * ev[j];
    }
    atomicAdd(&out2[(size_t)prev * 64 + lane], acc);
    if (lane < 19) atomicAdd(&acc2[(size_t)prev * 20 + lane], accS);
}

// ---------------- conv2 finalize + pool (fused): beta, relu, pooled atomics -
__global__ void finalize2x(const float* __restrict__ out2, const float* __restrict__ acc2,
                           const float* __restrict__ xr2, const float* __restrict__ We2,
                           const float* __restrict__ Wb2, const int* __restrict__ batch,
                           float* __restrict__ pooled) {
    __shared__ float w2s[EDIM * 64];
    int t = threadIdx.x;
    for (int i = t; i < EDIM * 64; i += 256) w2s[i] = We2[i];
    __syncthreads();
    int node = blockIdx.x * 4 + (t >> 6);
    int lane = t & 63;
    const float* a2 = acc2 + (size_t)node * 20;
    float num = out2[(size_t)node * 64 + lane];
    #pragma unroll
    for (int j = 0; j < EDIM; ++j) num += a2[j] * w2s[j * 64 + lane];
    float o = num / (a2[18] + 1e-16f);
    float xr = xr2[(size_t)node * 64 + lane];
    float part = o * Wb2[lane] + xr * Wb2[64 + lane] + (o - xr) * Wb2[128 + lane];
    #pragma unroll
    for (int off = 32; off; off >>= 1) part += __shfl_xor(part, off);
    float beta = 1.f / (1.f + __expf(-part));
    float hh = fmaxf(beta * xr + (1.f - beta) * o, 0.f);
    atomicAdd(&pooled[batch[node] * 64 + lane], hh);
}

// ---------------- final linear (cnt from graph bounds) ----------------
__global__ void final_lin(const float* __restrict__ pooled, const int* __restrict__ gs,
                          const int* __restrict__ ge,
                          const float* __restrict__ Wlin, const float* __restrict__ blin,
                          float* __restrict__ out) {
    int t = threadIdx.x;
    if (t >= N_GRAPHS * OUTF) return;
    int g = t / OUTF, o = t % OUTF;
    int c = ge[g] - gs[g];
    float inv = 1.f / fmaxf((float)c, 1.f);
    float acc = 0.f;
    for (int kk = 0; kk < HIDC; ++kk) acc += pooled[g * 64 + kk] * Wlin[kk * OUTF + o];
    out[t] = acc * inv + blin[o];
}

extern "C" void kernel_launch(void* const* d_in, const int* in_sizes, int n_in,
                              void* d_out, int out_size, void* d_ws, size_t ws_size,
                              hipStream_t stream) {
    const float* x      = (const float*)d_in[0];
    const int*   ei     = (const int*)d_in[1];
    const float* ea     = (const float*)d_in[2];
    const int*   batch  = (const int*)d_in[3];
    const float* Wq1    = (const float*)d_in[4];  const float* bq1    = (const float*)d_in[5];
    const float* Wk1    = (const float*)d_in[6];  const float* bk1    = (const float*)d_in[7];
    const float* Wv1    = (const float*)d_in[8];  const float* bv1    = (const float*)d_in[9];
    const float* We1    = (const float*)d_in[10];
    const float* Wskip1 = (const float*)d_in[11]; const float* bskip1 = (const float*)d_in[12];
    const float* Wbeta1 = (const float*)d_in[13];
    const float* Wq2    = (const float*)d_in[14]; const float* bq2    = (const float*)d_in[15];
    const float* Wk2    = (const float*)d_in[16]; const float* bk2    = (const float*)d_in[17];
    const float* Wv2    = (const float*)d_in[18]; const float* bv2    = (const float*)d_in[19];
    const float* We2    = (const float*)d_in[20];
    const float* Wskip2 = (const float*)d_in[21]; const float* bskip2 = (const float*)d_in[22];
    const float* Wbeta2 = (const float*)d_in[23];
    const float* Wlin   = (const float*)d_in[24]; const float* blin   = (const float*)d_in[25];

    float* ptr = (float*)d_ws;
    float* q2     = ptr; ptr += (size_t)N_NODES * 64;
    float* k2     = ptr; ptr += (size_t)N_NODES * 64;
    float* xr2    = ptr; ptr += (size_t)N_NODES * 64;
    float* qe     = ptr; ptr += (size_t)N_NODES * 32;
    __half* v2h   = (__half*)ptr; ptr += (size_t)N_NODES * 32;
    float* ea_s   = ptr; ptr += (size_t)N_EDGES * EPAD;
    float* alpha2 = ptr; ptr += N_EDGES;
    float* acc2   = ptr; ptr += (size_t)N_NODES * 20;
    float* out2   = ptr; ptr += (size_t)N_NODES * 64;
    float* pooled = ptr; ptr += N_GRAPHS * HIDC;
    int*   gs     = (int*)ptr; ptr += N_GRAPHS;
    int*   ge     = (int*)ptr; ptr += N_GRAPHS;
    float* cbuf   = ptr; ptr += 256;
    float* bias   = ptr; ptr += 320;                 // 288 used
    __half* Bt    = (__half*)ptr; ptr += (288 * 256) / 2;
    int*   src_s  = (int*)ptr; ptr += N_EDGES;
    int*   dst_s  = (int*)ptr; ptr += N_EDGES;
    int*   inv    = (int*)ptr; ptr += N_EDGES;
    int*   deg    = (int*)ptr; ptr += N_NODES;
    int*   cursor = (int*)ptr; ptr += N_NODES;
    float* coef   = ptr; ptr += (size_t)N_NODES * 84;
    float* acc1   = ptr; ptr += (size_t)N_NODES * 84;
    float* alpha1 = ptr; ptr += (size_t)4 * N_EDGES;
    __half* h1f   = (__half*)ptr; ptr += (size_t)N_NODES * 128;  // N*256 halfs

    const int EB = (N_EDGES + 255) / 256;

    // ---- weights + init + CSR ----
    prep_w<<<289, 256, 0, stream>>>(Wq2, bq2, Wk2, bk2, Wv2, bv2, Wskip2, bskip2, We2,
                                    Wq1, bq1, Wk1, bk1, We1, Bt, bias, cbuf);
    initA<<<(N_NODES * 84) / 256, 256, 0, stream>>>(x, cbuf, coef, acc1, acc2, out2,
                                                    deg, pooled, gs, ge);
    hist_kernel<<<EB, 256, 0, stream>>>(ei, deg, batch, gs, ge);
    scan_kernel<<<1, 1024, 0, stream>>>(deg, cursor);
    perm_kernel<<<EB, 256, 0, stream>>>(ei, cursor, inv);
    gatherE<<<EB, 256, 0, stream>>>(inv, ei, ea, x, coef, src_s, dst_s, ea_s, alpha1);

    // ---- conv1 ----
    strip1<<<(N_EDGES / 16) / 2, 256, 0, stream>>>(dst_s, alpha1, ea_s, acc1);
    finalize1x<<<N_NODES / 4, 256, 0, stream>>>(x, acc1, Wv1, bv1, We1, Wskip1, bskip1,
                                                Wbeta1, h1f);

    // ---- conv2 ----
    nl2_mfma<<<N_NODES / 64, 256, 0, stream>>>(h1f, Bt, bias, q2, k2, v2h, xr2, qe);
    logits2<<<LG2_BLOCKS, 256, 0, stream>>>(src_s, dst_s, ea_s, q2, k2, qe, alpha2);
    spmm2s<<<(N_EDGES / 16) / 4, 256, 0, stream>>>(dst_s, src_s, alpha2, v2h, ea_s,
                                                   out2, acc2);
    finalize2x<<<N_NODES / 4, 256, 0, stream>>>(out2, acc2, xr2, We2, Wbeta2, batch, pooled);

    // ---- head ----
    final_lin<<<1, 256, 0, stream>>>(pooled, gs, ge, Wlin, blin, (float*)d_out);
}

// Round 11
// 436.765 us; speedup vs baseline: 1.2126x; 1.2126x over previous
//
#include <hip/hip_runtime.h>
#include <hip/hip_fp16.h>

#define N_NODES 40000
#define N_EDGES 400000
#define N_GRAPHS 64
#define D1 256      // heads*hid for conv1
#define HIDC 64
#define NHEADS 4
#define EDIM 18
#define EPAD 20     // padded ea_s row stride; slots 18,19 hold x[src]
#define OUTF 3
#define APAD 264    // LDS row stride in halfs (256 + 8 pad -> 2-way bank alias only)

typedef _Float16 f16x8 __attribute__((ext_vector_type(8)));
typedef float f32x4 __attribute__((ext_vector_type(4)));

// ---------------- prep: pack conv2 weights + conv1 cbuf (one launch) --------
__global__ void prep_w(const float* __restrict__ Wq, const float* __restrict__ bq,
                       const float* __restrict__ Wk, const float* __restrict__ bk,
                       const float* __restrict__ Wv, const float* __restrict__ bv,
                       const float* __restrict__ Ws, const float* __restrict__ bs,
                       const float* __restrict__ We2,
                       const float* __restrict__ Wq1, const float* __restrict__ bq1,
                       const float* __restrict__ Wk1, const float* __restrict__ bk1,
                       const float* __restrict__ We1,
                       __half* __restrict__ Bt, float* __restrict__ bias,
                       float* __restrict__ cbuf) {
    int c = blockIdx.x, k = threadIdx.x;
    if (c < 256) {
        int m = c >> 6, d = c & 63;
        const float* W = (m == 0) ? Wq : (m == 1) ? Wk : (m == 2) ? Wv : Ws;
        Bt[c * 256 + k] = __float2half(W[k * 64 + d]);
        if (k == 0) {
            const float* b = (m == 0) ? bq : (m == 1) ? bk : (m == 2) ? bv : bs;
            bias[c] = b[d];
        }
    } else if (c < 288) {
        int j = c - 256;
        float s = 0.f;
        if (j < EDIM)
            for (int cc = 0; cc < 64; ++cc) s += Wq[k * 64 + cc] * We2[j * 64 + cc];
        Bt[c * 256 + k] = __float2half(s);
        if (k == 0) {
            float b = 0.f;
            if (j < EDIM)
                for (int cc = 0; cc < 64; ++cc) b += bq[cc] * We2[j * 64 + cc];
            bias[c] = b;
        }
    } else {
        int t = k;
        if (t < 36) {
            int h = t / 9, r = t % 9, a = r / 3, b = r % 3;
            const float* A = (a == 0) ? Wq1 : (a == 1) ? Wq1 + D1 : bq1;
            const float* B = (b == 0) ? Wk1 : (b == 1) ? Wk1 + D1 : bk1;
            float s = 0.f;
            for (int cc = 0; cc < 64; ++cc) s += A[h * 64 + cc] * B[h * 64 + cc];
            cbuf[h * 63 + a * 3 + b] = s;
        } else if (t < 252) {
            int i = t - 36;
            int h = i / 54, rr = (i % 54) / 18, j = i % 18;
            const float* A = (rr == 0) ? Wq1 : (rr == 1) ? Wq1 + D1 : bq1;
            float s = 0.f;
            for (int cc = 0; cc < 64; ++cc) s += A[h * 64 + cc] * We1[j * D1 + h * 64 + cc];
            cbuf[h * 63 + 9 + rr * 18 + j] = s;
        }
    }
}

// ---------------- init + conv1 coef table (merged) ----------------
__global__ void initA(const float* __restrict__ x, const float* __restrict__ cbuf,
                      float* __restrict__ coef, float* __restrict__ acc1,
                      float* __restrict__ acc2, float* __restrict__ out2,
                      int* __restrict__ deg, float* __restrict__ pooled,
                      int* __restrict__ gs, int* __restrict__ ge) {
    int t = blockIdx.x * 256 + threadIdx.x;      // N*84 threads exact
    acc1[t] = 0.f;
    {
        int n = t / 84, r = t % 84, h = r / 21, c = r % 21;
        const float* cb = cbuf + h * 63;
        float x0 = x[2 * n], x1 = x[2 * n + 1], o;
        if (c < 3) o = x0 * cb[c] + x1 * cb[3 + c] + cb[6 + c];
        else { int j = c - 3; o = x0 * cb[9 + j] + x1 * cb[27 + j] + cb[45 + j]; }
        coef[t] = o;
    }
    if (t < N_NODES * 64) out2[t] = 0.f;
    if (t < N_NODES * 20) acc2[t] = 0.f;
    if (t < N_NODES) deg[t] = 0;
    if (t < N_GRAPHS * HIDC) pooled[t] = 0.f;
    if (t < N_GRAPHS) { gs[t] = 0; ge[t] = 0; }
}

// ---------------- CSR hist + graph bounds (merged) ----------------
__global__ void hist_kernel(const int* __restrict__ ei, int* __restrict__ deg,
                            const int* __restrict__ batch, int* __restrict__ gs,
                            int* __restrict__ ge) {
    int e = blockIdx.x * 256 + threadIdx.x;
    if (e < N_EDGES) atomicAdd(&deg[ei[N_EDGES + e]], 1);
    int n = e;
    if (n < N_NODES) {
        int b = batch[n];
        if (n == 0) gs[b] = 0;
        else { int pb = batch[n - 1]; if (pb != b) { ge[pb] = n; gs[b] = n; } }
        if (n == N_NODES - 1) ge[b] = N_NODES;
    }
}

// ---------------- 3-kernel coalesced scan -> cursor ----------------
__global__ void scanA(const int* __restrict__ deg, int* __restrict__ bsum) {
    __shared__ int s[256];
    int b = blockIdx.x, t = threadIdx.x;
    s[t] = (t < 160) ? deg[b * 160 + t] : 0;
    __syncthreads();
    for (int off = 128; off; off >>= 1) {
        if (t < off) s[t] += s[t + off];
        __syncthreads();
    }
    if (t == 0) bsum[b] = s[0];
}

__global__ void scanB(const int* __restrict__ bsum, int* __restrict__ boff) {
    __shared__ int s[256];
    int t = threadIdx.x;
    int v = (t < 250) ? bsum[t] : 0;
    s[t] = v;
    __syncthreads();
    for (int off = 1; off < 256; off <<= 1) {
        int add = (t >= off) ? s[t - off] : 0;
        __syncthreads();
        s[t] += add;
        __syncthreads();
    }
    if (t < 250) boff[t] = s[t] - v;             // exclusive
}

__global__ void scanC(const int* __restrict__ deg, const int* __restrict__ boff,
                      int* __restrict__ cursor) {
    __shared__ int s[256];
    int b = blockIdx.x, t = threadIdx.x;
    int v = (t < 160) ? deg[b * 160 + t] : 0;
    s[t] = v;
    __syncthreads();
    for (int off = 1; off < 256; off <<= 1) {
        int add = (t >= off) ? s[t - off] : 0;
        __syncthreads();
        s[t] += add;
        __syncthreads();
    }
    if (t < 160) cursor[b * 160 + t] = boff[b] + s[t] - v;
}

// ---------------- 2-phase CSR scatter: perm (4B) then coalesced gather ------
__global__ void perm_kernel(const int* __restrict__ ei, int* __restrict__ cursor,
                            int* __restrict__ inv) {
    int e = blockIdx.x * 256 + threadIdx.x;
    if (e >= N_EDGES) return;
    int p = atomicAdd(&cursor[ei[N_EDGES + e]], 1);
    inv[p] = e;
}

// ---------------- fused gather + conv1 logits (4 heads) ----------------
__global__ void gatherE(const int* __restrict__ inv, const int* __restrict__ ei,
                        const float* __restrict__ ea, const float* __restrict__ x,
                        const float* __restrict__ coef,
                        int* __restrict__ src_s, int* __restrict__ dst_s,
                        float* __restrict__ ea_s, float* __restrict__ alpha1) {
    int p = blockIdx.x * 256 + threadIdx.x;
    if (p >= N_EDGES) return;
    int e = inv[p];
    int src = ei[e], dst = ei[N_EDGES + e];
    src_s[p] = src;
    dst_s[p] = dst;
    const float* srow = ea + (size_t)e * EDIM;
    float s[EDIM];
    #pragma unroll
    for (int j = 0; j < EDIM; ++j) s[j] = srow[j];
    float x0 = x[src * 2], x1 = x[src * 2 + 1];
    float4* drow = (float4*)(ea_s + (size_t)p * EPAD);
    drow[0] = make_float4(s[0],  s[1],  s[2],  s[3]);
    drow[1] = make_float4(s[4],  s[5],  s[6],  s[7]);
    drow[2] = make_float4(s[8],  s[9],  s[10], s[11]);
    drow[3] = make_float4(s[12], s[13], s[14], s[15]);
    drow[4] = make_float4(s[16], s[17], x0, x1);
    const float* cb = coef + (size_t)dst * 84;
    #pragma unroll
    for (int h = 0; h < NHEADS; ++h) {
        const float* c = cb + h * 21;
        float a = x0 * c[0] + x1 * c[1] + c[2];
        #pragma unroll
        for (int j = 0; j < EDIM; ++j) a += s[j] * c[3 + j];
        alpha1[(size_t)h * N_EDGES + p] = __expf(a * 0.125f);
    }
}

// ---------------- conv1: 16-edge strip, preloaded segmented reduction -------
__global__ void strip1(const int* __restrict__ dst_s, const float* __restrict__ alpha1,
                       const float* __restrict__ ea_s, float* __restrict__ acc1) {
    int t = threadIdx.x;
    int strip = blockIdx.x * 2 + (t >> 7);       // 2 strips per 256-block
    int gl = t & 127;
    bool active = gl < 84;
    int cgl = active ? gl : 83;
    int h = cgl / 21, comp = cgl % 21;
    int voff = (comp == 0) ? 18 : (comp == 1) ? 19 : (comp - 3);
    bool isone = (comp == 2);
    int p0 = strip * 16;
    int dsts[16]; float w[16]; float v[16];
    #pragma unroll
    for (int j = 0; j < 16; ++j) dsts[j] = dst_s[p0 + j];
    #pragma unroll
    for (int j = 0; j < 16; ++j) w[j] = alpha1[(size_t)h * N_EDGES + p0 + j];
    #pragma unroll
    for (int j = 0; j < 16; ++j) v[j] = isone ? 1.f : ea_s[(size_t)(p0 + j) * EPAD + voff];
    float acc = 0.f;
    int prev = dsts[0];
    #pragma unroll
    for (int j = 0; j < 16; ++j) {
        if (dsts[j] != prev) {
            if (active) atomicAdd(&acc1[(size_t)prev * 84 + gl], acc);
            acc = 0.f; prev = dsts[j];
        }
        acc += w[j] * v[j];
    }
    if (active) atomicAdd(&acc1[(size_t)prev * 84 + gl], acc);
}

// ---------------- conv1 finalize: 4 nodes/block, weights in regs ------------
__global__ void finalize1x(const float* __restrict__ x, const float* __restrict__ acc1,
                           const float* __restrict__ Wv, const float* __restrict__ bv,
                           const float* __restrict__ We, const float* __restrict__ Wskip,
                           const float* __restrict__ bskip, const float* __restrict__ Wbeta,
                           __half* __restrict__ h1f) {
    __shared__ float red[4][4];
    int nb = blockIdx.x * 4;
    int t = threadIdx.x;                          // column d
    int h = t >> 6;
    float wv0 = Wv[t], wv1 = Wv[D1 + t], bvv = bv[t];
    float we[EDIM];
    #pragma unroll
    for (int j = 0; j < EDIM; ++j) we[j] = We[j * D1 + t];
    float ws0 = Wskip[t], ws1 = Wskip[D1 + t], bsv = bskip[t];
    float wb0 = Wbeta[t], wb1 = Wbeta[D1 + t], wb2 = Wbeta[2 * D1 + t];
    float o[4], xr[4], part[4];
    #pragma unroll
    for (int i = 0; i < 4; ++i) {
        int node = nb + i;
        const float* a = acc1 + (size_t)node * 84 + h * 21;
        float l = a[2];
        float oo = a[0] * wv0 + a[1] * wv1 + l * bvv;
        #pragma unroll
        for (int j = 0; j < EDIM; ++j) oo += a[3 + j] * we[j];
        oo /= (l + 1e-16f);
        float x0 = x[node * 2], x1 = x[node * 2 + 1];
        xr[i] = x0 * ws0 + x1 * ws1 + bsv;
        o[i] = oo;
        part[i] = oo * wb0 + xr[i] * wb1 + (oo - xr[i]) * wb2;
    }
    #pragma unroll
    for (int off = 32; off; off >>= 1) {
        #pragma unroll
        for (int i = 0; i < 4; ++i) part[i] += __shfl_xor(part[i], off);
    }
    if ((t & 63) == 0) {
        #pragma unroll
        for (int i = 0; i < 4; ++i) red[h][i] = part[i];
    }
    __syncthreads();
    #pragma unroll
    for (int i = 0; i < 4; ++i) {
        float tot = red[0][i] + red[1][i] + red[2][i] + red[3][i];
        float beta = 1.f / (1.f + __expf(-tot));
        h1f[(size_t)(nb + i) * D1 + t] =
            __float2half(fmaxf(beta * xr[i] + (1.f - beta) * o[i], 0.f));
    }
}

// ---------------- conv2 linears via MFMA, LDS-staged A ----------------------
__device__ __forceinline__ void nl2_store(int c, int gr, float v,
        float* __restrict__ q2, float* __restrict__ k2, __half* __restrict__ v2h,
        float* __restrict__ xr2, float* __restrict__ qe) {
    if (c < 256) {
        int m = c >> 6, d = c & 63;
        if (m == 0)      q2[(size_t)gr * 64 + d] = v;
        else if (m == 1) k2[(size_t)gr * 64 + d] = v;
        else if (m == 2) v2h[(size_t)gr * 64 + d] = __float2half(v);
        else             xr2[(size_t)gr * 64 + d] = v;
    } else {
        qe[(size_t)gr * 32 + (c - 256)] = v;
    }
}

__global__ __launch_bounds__(256) void nl2_mfma(
        const __half* __restrict__ h1f, const __half* __restrict__ Bt,
        const float* __restrict__ bias,
        float* __restrict__ q2, float* __restrict__ k2,
        __half* __restrict__ v2h, float* __restrict__ xr2,
        float* __restrict__ qe) {
    __shared__ _Float16 As[64 * APAD];
    int t = threadIdx.x;
    int row0 = blockIdx.x * 64;
    const float4* gsrc = (const float4*)(h1f + (size_t)row0 * 256);
    #pragma unroll
    for (int i = 0; i < 8; ++i) {
        int li = i * 256 + t;                 // chunk of 8 halfs
        int r = li >> 5, c8 = li & 31;
        *(float4*)(As + r * APAD + c8 * 8) = gsrc[li];
    }
    __syncthreads();
    int wave = t >> 6, lane = t & 63, quad = lane >> 4, mm = lane & 15;
    const _Float16* Bp = (const _Float16*)Bt;
    for (int ct = wave; ct < 18; ct += 4) {
        int c0 = ct * 16 + mm;
        const _Float16* b0 = Bp + (size_t)c0 * 256 + quad * 8;
        f16x8 b[8];
        #pragma unroll
        for (int s = 0; s < 8; ++s) b[s] = *(const f16x8*)(b0 + s * 32);
        float bz = bias[c0];
        #pragma unroll
        for (int rt = 0; rt < 4; ++rt) {
            const _Float16* arow = As + (rt * 16 + mm) * APAD + quad * 8;
            f16x8 a[8];
            #pragma unroll
            for (int s = 0; s < 8; ++s) a[s] = *(const f16x8*)(arow + s * 32);
            f32x4 accA = {bz, bz, bz, bz};
            f32x4 accB = {0.f, 0.f, 0.f, 0.f};
            #pragma unroll
            for (int s = 0; s < 4; ++s) {
                accA = __builtin_amdgcn_mfma_f32_16x16x32_f16(a[s],     b[s],     accA, 0, 0, 0);
                accB = __builtin_amdgcn_mfma_f32_16x16x32_f16(a[s + 4], b[s + 4], accB, 0, 0, 0);
            }
            #pragma unroll
            for (int r = 0; r < 4; ++r) {
                int gr = row0 + rt * 16 + quad * 4 + r;
                nl2_store(c0, gr, accA[r] + accB[r], q2, k2, v2h, xr2, qe);
            }
        }
    }
}

// ---------------- conv2: wave-per-edge logits, 2-edge unroll ----------------
#define LG2_BLOCKS 2048
#define LG2_WAVES (LG2_BLOCKS * 4)
__global__ void logits2(const int* __restrict__ src_s, const int* __restrict__ dst_s,
                        const float* __restrict__ ea_s, const float* __restrict__ q2,
                        const float* __restrict__ k2, const float* __restrict__ qe,
                        float* __restrict__ alpha2) {
    int t = threadIdx.x, wid = t >> 6, lane = t & 63;
    int w = blockIdx.x * 4 + wid;
    for (int base = w; base < N_EDGES; base += 2 * LG2_WAVES) {
        int p1 = base, p2 = base + LG2_WAVES;
        bool has2 = p2 < N_EDGES;
        int p2c = has2 ? p2 : p1;
        int s1 = src_s[p1], d1 = dst_s[p1];
        int s2 = src_s[p2c], d2 = dst_s[p2c];
        float dd1 = q2[(size_t)d1 * 64 + lane] * k2[(size_t)s1 * 64 + lane];
        float dd2 = q2[(size_t)d2 * 64 + lane] * k2[(size_t)s2 * 64 + lane];
        if (lane < 20) {
            dd1 += qe[(size_t)d1 * 32 + lane] * ea_s[(size_t)p1 * EPAD + lane];
            dd2 += qe[(size_t)d2 * 32 + lane] * ea_s[(size_t)p2c * EPAD + lane];
        }
        #pragma unroll
        for (int off = 32; off; off >>= 1) {
            dd1 += __shfl_xor(dd1, off);
            dd2 += __shfl_xor(dd2, off);
        }
        if (lane == 0) {
            alpha2[p1] = __expf(dd1 * 0.125f);
            if (has2) alpha2[p2] = __expf(dd2 * 0.125f);
        }
    }
}

// ---------------- conv2: 16-edge strip, preloaded: out2+=w*v, acc2+=w*[ea,1]-
__global__ void spmm2s(const int* __restrict__ dst_s, const int* __restrict__ src_s,
                       const float* __restrict__ alpha2, const __half* __restrict__ v2h,
                       const float* __restrict__ ea_s,
                       float* __restrict__ out2, float* __restrict__ acc2) {
    int t = threadIdx.x;
    int strip = blockIdx.x * 4 + (t >> 6);
    int lane = t & 63;
    int p0 = strip * 16;
    int dsts[16]; int srcs[16]; float w[16];
    #pragma unroll
    for (int j = 0; j < 16; ++j) dsts[j] = dst_s[p0 + j];
    #pragma unroll
    for (int j = 0; j < 16; ++j) srcs[j] = src_s[p0 + j];
    #pragma unroll
    for (int j = 0; j < 16; ++j) w[j] = alpha2[p0 + j];
    float vv[16]; float ev[16];
    #pragma unroll
    for (int j = 0; j < 16; ++j) vv[j] = __half2float(v2h[(size_t)srcs[j] * 64 + lane]);
    #pragma unroll
    for (int j = 0; j < 16; ++j)
        ev[j] = (lane < EDIM) ? ea_s[(size_t)(p0 + j) * EPAD + lane] : 1.f;
    float acc = 0.f, accS = 0.f;
    int prev = dsts[0];
    #pragma unroll
    for (int j = 0; j < 16; ++j) {
        if (dsts[j] != prev) {
            atomicAdd(&out2[(size_t)prev * 64 + lane], acc);
            if (lane < 19) atomicAdd(&acc2[(size_t)prev * 20 + lane], accS);
            acc = 0.f; accS = 0.f; prev = dsts[j];
        }
        acc += w[j] * vv[j];
        accS += w[j] * ev[j];
    }
    atomicAdd(&out2[(size_t)prev * 64 + lane], acc);
    if (lane < 19) atomicAdd(&acc2[(size_t)prev * 20 + lane], accS);
}

// ---------------- conv2 finalize: + e-term, normalize, beta, relu -> h2 -----
__global__ void finalize2x(const float* __restrict__ out2, const float* __restrict__ acc2,
                           const float* __restrict__ xr2, const float* __restrict__ We2,
                           const float* __restrict__ Wb2, float* __restrict__ h2) {
    __shared__ float w2s[EDIM * 64];
    int t = threadIdx.x;
    for (int i = t; i < EDIM * 64; i += 256) w2s[i] = We2[i];
    __syncthreads();
    int node = blockIdx.x * 4 + (t >> 6);
    int lane = t & 63;
    const float* a2 = acc2 + (size_t)node * 20;
    float num = out2[(size_t)node * 64 + lane];
    #pragma unroll
    for (int j = 0; j < EDIM; ++j) num += a2[j] * w2s[j * 64 + lane];
    float o = num / (a2[18] + 1e-16f);
    float xr = xr2[(size_t)node * 64 + lane];
    float part = o * Wb2[lane] + xr * Wb2[64 + lane] + (o - xr) * Wb2[128 + lane];
    #pragma unroll
    for (int off = 32; off; off >>= 1) part += __shfl_xor(part, off);
    float beta = 1.f / (1.f + __expf(-part));
    h2[(size_t)node * 64 + lane] = fmaxf(beta * xr + (1.f - beta) * o, 0.f);
}

// ---------------- pool: 4 blocks per graph, dense reads ----------------
__global__ void pool_kernel(const float* __restrict__ h2, const int* __restrict__ gs,
                            const int* __restrict__ ge, float* __restrict__ pooled) {
    __shared__ float red[4][64];
    int g = blockIdx.x >> 2, q = blockIdx.x & 3;
    int t = threadIdx.x, wv = t >> 6, lane = t & 63;
    int s = gs[g], e = ge[g];
    float sum = 0.f;
    for (int n = s + q * 4 + wv; n < e; n += 16) sum += h2[(size_t)n * 64 + lane];
    red[wv][lane] = sum;
    __syncthreads();
    if (wv == 0) {
        float v = red[0][lane] + red[1][lane] + red[2][lane] + red[3][lane];
        atomicAdd(&pooled[g * 64 + lane], v);
    }
}

// ---------------- final linear (cnt from graph bounds) ----------------
__global__ void final_lin(const float* __restrict__ pooled, const int* __restrict__ gs,
                          const int* __restrict__ ge,
                          const float* __restrict__ Wlin, const float* __restrict__ blin,
                          float* __restrict__ out) {
    int t = threadIdx.x;
    if (t >= N_GRAPHS * OUTF) return;
    int g = t / OUTF, o = t % OUTF;
    int c = ge[g] - gs[g];
    float inv = 1.f / fmaxf((float)c, 1.f);
    float acc = 0.f;
    for (int kk = 0; kk < HIDC; ++kk) acc += pooled[g * 64 + kk] * Wlin[kk * OUTF + o];
    out[t] = acc * inv + blin[o];
}

extern "C" void kernel_launch(void* const* d_in, const int* in_sizes, int n_in,
                              void* d_out, int out_size, void* d_ws, size_t ws_size,
                              hipStream_t stream) {
    const float* x      = (const float*)d_in[0];
    const int*   ei     = (const int*)d_in[1];
    const float* ea     = (const float*)d_in[2];
    const int*   batch  = (const int*)d_in[3];
    const float* Wq1    = (const float*)d_in[4];  const float* bq1    = (const float*)d_in[5];
    const float* Wk1    = (const float*)d_in[6];  const float* bk1    = (const float*)d_in[7];
    const float* Wv1    = (const float*)d_in[8];  const float* bv1    = (const float*)d_in[9];
    const float* We1    = (const float*)d_in[10];
    const float* Wskip1 = (const float*)d_in[11]; const float* bskip1 = (const float*)d_in[12];
    const float* Wbeta1 = (const float*)d_in[13];
    const float* Wq2    = (const float*)d_in[14]; const float* bq2    = (const float*)d_in[15];
    const float* Wk2    = (const float*)d_in[16]; const float* bk2    = (const float*)d_in[17];
    const float* Wv2    = (const float*)d_in[18]; const float* bv2    = (const float*)d_in[19];
    const float* We2    = (const float*)d_in[20];
    const float* Wskip2 = (const float*)d_in[21]; const float* bskip2 = (const float*)d_in[22];
    const float* Wbeta2 = (const float*)d_in[23];
    const float* Wlin   = (const float*)d_in[24]; const float* blin   = (const float*)d_in[25];

    float* ptr = (float*)d_ws;
    float* q2     = ptr; ptr += (size_t)N_NODES * 64;
    float* k2     = ptr; ptr += (size_t)N_NODES * 64;
    float* xr2    = ptr; ptr += (size_t)N_NODES * 64;
    float* qe     = ptr; ptr += (size_t)N_NODES * 32;
    __half* v2h   = (__half*)ptr; ptr += (size_t)N_NODES * 32;
    float* ea_s   = ptr; ptr += (size_t)N_EDGES * EPAD;
    float* alpha2 = ptr; ptr += N_EDGES;
    float* acc2   = ptr; ptr += (size_t)N_NODES * 20;
    float* out2   = ptr; ptr += (size_t)N_NODES * 64;
    float* pooled = ptr; ptr += N_GRAPHS * HIDC;
    int*   gs     = (int*)ptr; ptr += N_GRAPHS;
    int*   ge     = (int*)ptr; ptr += N_GRAPHS;
    float* cbuf   = ptr; ptr += 256;
    float* bias   = ptr; ptr += 320;                 // 288 used
    __half* Bt    = (__half*)ptr; ptr += (288 * 256) / 2;
    int*   src_s  = (int*)ptr; ptr += N_EDGES;
    int*   dst_s  = (int*)ptr; ptr += N_EDGES;
    int*   inv    = (int*)ptr; ptr += N_EDGES;
    int*   deg    = (int*)ptr; ptr += N_NODES;
    int*   cursor = (int*)ptr; ptr += N_NODES;
    int*   bsum   = (int*)ptr; ptr += 256;
    int*   boff   = (int*)ptr; ptr += 256;
    float* coef   = ptr; ptr += (size_t)N_NODES * 84;   // h2 aliases (coef dead)
    float* h2     = coef;
    float* acc1   = ptr; ptr += (size_t)N_NODES * 84;
    float* alpha1 = ptr; ptr += (size_t)4 * N_EDGES;
    __half* h1f   = (__half*)ptr; ptr += (size_t)N_NODES * 128;  // N*256 halfs

    const int EB = (N_EDGES + 255) / 256;

    // ---- weights + init + CSR ----
    prep_w<<<289, 256, 0, stream>>>(Wq2, bq2, Wk2, bk2, Wv2, bv2, Wskip2, bskip2, We2,
                                    Wq1, bq1, Wk1, bk1, We1, Bt, bias, cbuf);
    initA<<<(N_NODES * 84) / 256, 256, 0, stream>>>(x, cbuf, coef, acc1, acc2, out2,
                                                    deg, pooled, gs, ge);
    hist_kernel<<<EB, 256, 0, stream>>>(ei, deg, batch, gs, ge);
    scanA<<<250, 256, 0, stream>>>(deg, bsum);
    scanB<<<1, 256, 0, stream>>>(bsum, boff);
    scanC<<<250, 256, 0, stream>>>(deg, boff, cursor);
    perm_kernel<<<EB, 256, 0, stream>>>(ei, cursor, inv);
    gatherE<<<EB, 256, 0, stream>>>(inv, ei, ea, x, coef, src_s, dst_s, ea_s, alpha1);

    // ---- conv1 ----
    strip1<<<(N_EDGES / 16) / 2, 256, 0, stream>>>(dst_s, alpha1, ea_s, acc1);
    finalize1x<<<N_NODES / 4, 256, 0, stream>>>(x, acc1, Wv1, bv1, We1, Wskip1, bskip1,
                                                Wbeta1, h1f);

    // ---- conv2 ----
    nl2_mfma<<<N_NODES / 64, 256, 0, stream>>>(h1f, Bt, bias, q2, k2, v2h, xr2, qe);
    logits2<<<LG2_BLOCKS, 256, 0, stream>>>(src_s, dst_s, ea_s, q2, k2, qe, alpha2);
    spmm2s<<<(N_EDGES / 16) / 4, 256, 0, stream>>>(dst_s, src_s, alpha2, v2h, ea_s,
                                                   out2, acc2);
    finalize2x<<<N_NODES / 4, 256, 0, stream>>>(out2, acc2, xr2, We2, Wbeta2, h2);

    // ---- pool + head ----
    pool_kernel<<<N_GRAPHS * 4, 256, 0, stream>>>(h2, gs, ge, pooled);
    final_lin<<<1, 256, 0, stream>>>(pooled, gs, ge, Wlin, blin, (float*)d_out);
}